// Round 4
// baseline (67.531 us; speedup 1.0000x reference)
//
#include <hip/hip_runtime.h>
#include <hip/hip_bf16.h>
#include <math.h>
#include <stdint.h>

// ScaledDotProductAttention: B=2, H=16, S=2048, D=64, fp32 in/out.
// Round 4: two-kernel scheme.
//  1) prep_pack: fp32 K/V -> bf16 "LDS images" in d_ws. Each 64x64 tile is
//     stored exactly as the main kernel's LDS wants it (K row-major with
//     (r&7)<<3 XOR swizzle; V transposed [d][k] with (d&7)<<3 swizzle).
//  2) attn_fwd_lds: flash attention, 32x32x16 bf16 MFMA, swapped QK^T,
//     in-register P (cvt_pk_bf16 + permlane32_swap), defer-max, and
//     global_load_lds(16B) staging of the pre-baked tiles: zero staging VALU,
//     linear LDS writes (no write bank conflicts).
// Fallback: if ws_size too small, round-3 kernel (reg-staged, proven).

#define S_LEN 2048
#define DK 64
#define QW 32
#define NW 4
#define QBLK (QW * NW)          // 128
#define KVBLK 64
#define NT (S_LEN / KVBLK)      // 32
#define LOG2E 1.44269504088896340736f
#define THR 8.0f

typedef __attribute__((ext_vector_type(16))) float f32x16;
typedef __attribute__((ext_vector_type(8)))  __bf16 bf16x8;
typedef __attribute__((ext_vector_type(4)))  __bf16 bf16x4;
typedef __attribute__((ext_vector_type(4)))  uint32_t u32x4;

union frag_cast { u32x4 u; bf16x8 h; };

__device__ __forceinline__ uint32_t cvt_pk_bf16(float lo, float hi) {
    uint32_t r;
    asm("v_cvt_pk_bf16_f32 %0, %1, %2" : "=v"(r) : "v"(lo), "v"(hi));
    return r;
}
__device__ __forceinline__ void perm32swap(uint32_t& a, uint32_t& b) {
    asm volatile("v_permlane32_swap_b32 %0, %1" : "+v"(a), "+v"(b));
}
__device__ __forceinline__ void load_lds16(const __bf16* g, __bf16* l) {
    __builtin_amdgcn_global_load_lds(
        (const __attribute__((address_space(1))) void*)g,
        (__attribute__((address_space(3))) void*)l, 16, 0, 0);
}
__device__ __forceinline__ bf16x8 pack8(float4 a, float4 b) {
    bf16x8 f;
    f[0] = (__bf16)a.x; f[1] = (__bf16)a.y; f[2] = (__bf16)a.z; f[3] = (__bf16)a.w;
    f[4] = (__bf16)b.x; f[5] = (__bf16)b.y; f[6] = (__bf16)b.z; f[7] = (__bf16)b.w;
    return f;
}

// ---------------- prepass: build bf16 LDS images of K and V tiles ----------
// Kimg[bh][t][r][y] = K[bh][t*64+r][y ^ 8*(r&7)]      (4096 bf16 per tile)
// Vimg[bh][t][d][y] = V[bh][t*64 + (y ^ 8*(d&7))][d]
__global__ __launch_bounds__(256)
void prep_pack(const float* __restrict__ Kg, const float* __restrict__ Vg,
               __bf16* __restrict__ Kimg, __bf16* __restrict__ Vimg)
{
    __shared__ float Vs[64 * 65];
    const int tid = threadIdx.x;
    const int t = blockIdx.x, bh = blockIdx.y;
    const size_t ibase = ((size_t)bh * S_LEN + (size_t)t * 64) * DK; // fp32 elems
    const size_t obase = ((size_t)bh * NT + t) * 4096;               // bf16 elems

    // ---- K: convert + bake read-swizzle (8-elem granule, involution) ----
    #pragma unroll
    for (int u = 0; u < 2; ++u) {
        const int rho = tid + 256 * u;           // 0..511, 8-elem runs
        const int r = rho >> 3, j = rho & 7;
        const float* src = Kg + ibase + r * 64 + j * 8;
        float4 a = *(const float4*)(src);
        float4 b = *(const float4*)(src + 4);
        *(bf16x8*)(Kimg + obase + r * 64 + ((j * 8) ^ ((r & 7) << 3))) = pack8(a, b);
    }

    // ---- V: stage tile to LDS (fp32, padded 65), then transposed pack ----
    {
        const int r = tid >> 2, c0 = (tid & 3) * 16;
        const float* src = Vg + ibase + r * 64 + c0;
        #pragma unroll
        for (int m = 0; m < 4; ++m) {
            float4 x = *(const float4*)(src + 4 * m);
            float* dst = &Vs[r * 65 + c0 + 4 * m];
            dst[0] = x.x; dst[1] = x.y; dst[2] = x.z; dst[3] = x.w;
        }
    }
    __syncthreads();
    #pragma unroll
    for (int u = 0; u < 2; ++u) {
        const int rho = tid + 256 * u;           // 0..511
        const int d = rho >> 3, j = rho & 7;
        const int k0 = 8 * (j ^ (d & 7));        // (8j+i) ^ 8*(d&7) = k0+i
        bf16x8 wv;
        #pragma unroll
        for (int i = 0; i < 8; ++i) wv[i] = (__bf16)Vs[(k0 + i) * 65 + d];
        *(bf16x8*)(Vimg + obase + d * 64 + j * 8) = wv;
    }
}

// ---------------- main kernel: global_load_lds staged flash attention ------
__global__ __launch_bounds__(256, 2)
void attn_fwd_lds(const float* __restrict__ Qg, const __bf16* __restrict__ Kimg,
                  const __bf16* __restrict__ Vimg, float* __restrict__ Og)
{
    __shared__ __align__(16) __bf16 Kl[2][4096];
    __shared__ __align__(16) __bf16 Vt[2][4096];

    const int tid = threadIdx.x;
    const int lane = tid & 63;
    const int w   = tid >> 6;
    const int l31 = lane & 31;
    const int hi  = lane >> 5;

    const int qt = blockIdx.x;
    const int bh = blockIdx.y;
    const size_t base = (size_t)bh * (S_LEN * DK);
    const int q0g = qt * QBLK + w * QW;

    // ---- Q fragments (B-operand): lane holds Q[q0g+l31][16*sp + 8*hi + i],
    // scale 1/8 * log2(e) folded (once per block, amortized over 32 tiles).
    bf16x8 qf[4];
    {
        const float sc = 0.125f * LOG2E;
        const float* qrow = Qg + base + (size_t)(q0g + l31) * DK;
        #pragma unroll
        for (int sp = 0; sp < 4; ++sp) {
            const int d0 = 16 * sp + 8 * hi;
            float4 a = *(const float4*)(qrow + d0);
            float4 b = *(const float4*)(qrow + d0 + 4);
            bf16x8 f;
            f[0] = (__bf16)(a.x * sc); f[1] = (__bf16)(a.y * sc);
            f[2] = (__bf16)(a.z * sc); f[3] = (__bf16)(a.w * sc);
            f[4] = (__bf16)(b.x * sc); f[5] = (__bf16)(b.y * sc);
            f[6] = (__bf16)(b.z * sc); f[7] = (__bf16)(b.w * sc);
            qf[sp] = f;
        }
    }

    f32x16 acc0 = {}, acc1 = {};
    float m_run = -INFINITY, l_run = 0.f;

    const __bf16* kbase = Kimg + (size_t)bh * NT * 4096;
    const __bf16* vbase = Vimg + (size_t)bh * NT * 4096;

    auto stage = [&](int t, int b) {
        const __bf16* kt = kbase + (size_t)t * 4096 + tid * 8;
        const __bf16* vt = vbase + (size_t)t * 4096 + tid * 8;
        load_lds16(kt,        &Kl[b][w * 512]);
        load_lds16(kt + 2048, &Kl[b][2048 + w * 512]);
        load_lds16(vt,        &Vt[b][w * 512]);
        load_lds16(vt + 2048, &Vt[b][2048 + w * 512]);
    };

    stage(0, 0);
    __syncthreads();   // drains vmcnt -> tile 0 resident

    int cur = 0;
    #pragma unroll 1
    for (int t = 0; t < NT; ++t) {
        if (t + 1 < NT) stage(t + 1, cur ^ 1);   // in flight across compute

        // ---- S^T = K Q^T ----
        f32x16 s0 = {}, s1 = {};
        __builtin_amdgcn_s_setprio(1);
        #pragma unroll
        for (int sp = 0; sp < 4; ++sp) {
            #pragma unroll
            for (int kt2 = 0; kt2 < 2; ++kt2) {
                const int krow = kt2 * 32 + l31;
                const int eo = krow * 64 + ((16 * sp + 8 * hi) ^ ((krow & 7) << 3));
                bf16x8 kb = *(const bf16x8*)(&Kl[cur][eo]);
                if (kt2 == 0) s0 = __builtin_amdgcn_mfma_f32_32x32x16_bf16(kb, qf[sp], s0, 0, 0, 0);
                else          s1 = __builtin_amdgcn_mfma_f32_32x32x16_bf16(kb, qf[sp], s1, 0, 0, 0);
            }
        }
        __builtin_amdgcn_s_setprio(0);

        // ---- lane-local online softmax (q = l31), defer-max ----
        float vmax = -INFINITY;
        #pragma unroll
        for (int j = 0; j < 16; ++j) vmax = fmaxf(vmax, s0[j]);
        #pragma unroll
        for (int j = 0; j < 16; ++j) vmax = fmaxf(vmax, s1[j]);
        vmax = fmaxf(vmax, __shfl_xor(vmax, 32));

        if (!__all(vmax - m_run <= THR)) {
            const float mnew = fmaxf(m_run, vmax);
            const float alpha = __builtin_amdgcn_exp2f(m_run - mnew);
            m_run = mnew;
            l_run *= alpha;
            #pragma unroll
            for (int r = 0; r < 16; ++r) {
                const int ql = (r & 3) + 8 * (r >> 2) + 4 * hi;
                const float ar = __shfl(alpha, ql + (hi << 5));
                acc0[r] *= ar;
                acc1[r] *= ar;
            }
        }

        float rs = 0.f;
        #pragma unroll
        for (int j = 0; j < 16; ++j) { const float p = __builtin_amdgcn_exp2f(s0[j] - m_run); s0[j] = p; rs += p; }
        #pragma unroll
        for (int j = 0; j < 16; ++j) { const float p = __builtin_amdgcn_exp2f(s1[j] - m_run); s1[j] = p; rs += p; }
        rs += __shfl_xor(rs, 32);
        l_run += rs;

        // ---- P -> bf16 A-frags in-register ----
        frag_cast pa[4];
        #pragma unroll
        for (int b2 = 0; b2 < 2; ++b2) {
            #pragma unroll
            for (int st = 0; st < 2; ++st) {
                uint32_t wa, wb, wc, wd;
                if (b2 == 0) {
                    wa = cvt_pk_bf16(s0[8 * st + 0], s0[8 * st + 1]);
                    wb = cvt_pk_bf16(s0[8 * st + 2], s0[8 * st + 3]);
                    wc = cvt_pk_bf16(s0[8 * st + 4], s0[8 * st + 5]);
                    wd = cvt_pk_bf16(s0[8 * st + 6], s0[8 * st + 7]);
                } else {
                    wa = cvt_pk_bf16(s1[8 * st + 0], s1[8 * st + 1]);
                    wb = cvt_pk_bf16(s1[8 * st + 2], s1[8 * st + 3]);
                    wc = cvt_pk_bf16(s1[8 * st + 4], s1[8 * st + 5]);
                    wd = cvt_pk_bf16(s1[8 * st + 6], s1[8 * st + 7]);
                }
                perm32swap(wa, wc);
                perm32swap(wb, wd);
                pa[2 * b2 + st].u = (u32x4){wa, wb, wc, wd};
            }
        }

        // ---- O += P V ----
        __builtin_amdgcn_s_setprio(1);
        #pragma unroll
        for (int ks = 0; ks < 4; ++ks) {
            #pragma unroll
            for (int dt = 0; dt < 2; ++dt) {
                const int d = dt * 32 + l31;
                const int eo = d * 64 + ((16 * ks + 8 * hi) ^ ((d & 7) << 3));
                bf16x8 vb = *(const bf16x8*)(&Vt[cur][eo]);
                if (dt == 0) acc0 = __builtin_amdgcn_mfma_f32_32x32x16_bf16(pa[ks].h, vb, acc0, 0, 0, 0);
                else         acc1 = __builtin_amdgcn_mfma_f32_32x32x16_bf16(pa[ks].h, vb, acc1, 0, 0, 0);
            }
        }
        __builtin_amdgcn_s_setprio(0);

        __syncthreads();   // compiler drains vmcnt+lgkmcnt: next tile resident
        cur ^= 1;
    }

    float* op = Og + base;
    #pragma unroll
    for (int r = 0; r < 16; ++r) {
        const int ql = (r & 3) + 8 * (r >> 2) + 4 * hi;
        const float lr = __shfl(l_run, ql + (hi << 5));
        const float invl = 1.0f / lr;
        const size_t row = (size_t)(q0g + ql) * DK;
        op[row + l31]      = acc0[r] * invl;
        op[row + 32 + l31] = acc1[r] * invl;
    }
}

// ---------------- fallback (round-3 kernel, reg-staged) --------------------
__global__ __launch_bounds__(256, 2)
void attn_fwd_fb(const float* __restrict__ Qg, const float* __restrict__ Kg,
                 const float* __restrict__ Vg, float* __restrict__ Og)
{
    __shared__ __align__(16) __bf16 Kl[2][64 * 64];
    __shared__ __align__(16) __bf16 Vt[2][64 * 64];

    const int tid = threadIdx.x;
    const int lane = tid & 63;
    const int w   = tid >> 6;
    const int l31 = lane & 31;
    const int hi  = lane >> 5;

    const int qt = blockIdx.x;
    const int bh = blockIdx.y;
    const size_t base = (size_t)bh * (S_LEN * DK);
    const int q0g = qt * QBLK + w * QW;

    bf16x8 qf[4];
    {
        const float sc = 0.125f * LOG2E;
        const float* qrow = Qg + base + (size_t)(q0g + l31) * DK;
        #pragma unroll
        for (int sp = 0; sp < 4; ++sp) {
            const int d0 = 16 * sp + 8 * hi;
            float4 a = *(const float4*)(qrow + d0);
            float4 b = *(const float4*)(qrow + d0 + 4);
            bf16x8 f;
            f[0] = (__bf16)(a.x * sc); f[1] = (__bf16)(a.y * sc);
            f[2] = (__bf16)(a.z * sc); f[3] = (__bf16)(a.w * sc);
            f[4] = (__bf16)(b.x * sc); f[5] = (__bf16)(b.y * sc);
            f[6] = (__bf16)(b.z * sc); f[7] = (__bf16)(b.w * sc);
            qf[sp] = f;
        }
    }

    f32x16 acc0 = {}, acc1 = {};
    float m_run = -INFINITY, l_run = 0.f;

    float4 kpre[4];
    float  vpre[4][4];
    const int vd  = tid & 63;
    const int vkq = tid >> 6;

    auto issueLoads = [&](int t) {
        const int kv0 = t * KVBLK;
        #pragma unroll
        for (int i = 0; i < 4; ++i) {
            const int idx = tid + 256 * i;
            const int r = idx >> 4, c = idx & 15;
            kpre[i] = *(const float4*)(Kg + base + (size_t)(kv0 + r) * DK + c * 4);
        }
        #pragma unroll
        for (int i = 0; i < 4; ++i) {
            const int k0 = vkq * 4 + 16 * i;
            const float* vp = Vg + base + (size_t)(kv0 + k0) * DK + vd;
            vpre[i][0] = vp[0];      vpre[i][1] = vp[DK];
            vpre[i][2] = vp[2 * DK]; vpre[i][3] = vp[3 * DK];
        }
    };
    auto writeTile = [&](int b) {
        #pragma unroll
        for (int i = 0; i < 4; ++i) {
            const int idx = tid + 256 * i;
            const int r = idx >> 4, c = idx & 15;
            bf16x4 pk;
            pk[0] = (__bf16)kpre[i].x; pk[1] = (__bf16)kpre[i].y;
            pk[2] = (__bf16)kpre[i].z; pk[3] = (__bf16)kpre[i].w;
            *(bf16x4*)(&Kl[b][r * 64 + ((c * 4) ^ ((r & 7) << 3))]) = pk;
        }
        #pragma unroll
        for (int i = 0; i < 4; ++i) {
            const int k0 = vkq * 4 + 16 * i;
            bf16x4 pv;
            pv[0] = (__bf16)vpre[i][0]; pv[1] = (__bf16)vpre[i][1];
            pv[2] = (__bf16)vpre[i][2]; pv[3] = (__bf16)vpre[i][3];
            *(bf16x4*)(&Vt[b][vd * 64 + (k0 ^ ((vd & 7) << 3))]) = pv;
        }
    };

    issueLoads(0);
    writeTile(0);
    __syncthreads();

    int cur = 0;
    #pragma unroll 1
    for (int t = 0; t < NT; ++t) {
        if (t + 1 < NT) issueLoads(t + 1);

        f32x16 s0 = {}, s1 = {};
        __builtin_amdgcn_s_setprio(1);
        #pragma unroll
        for (int sp = 0; sp < 4; ++sp) {
            #pragma unroll
            for (int kt2 = 0; kt2 < 2; ++kt2) {
                const int krow = kt2 * 32 + l31;
                const int eo = krow * 64 + ((16 * sp + 8 * hi) ^ ((krow & 7) << 3));
                bf16x8 kb = *(const bf16x8*)(&Kl[cur][eo]);
                if (kt2 == 0) s0 = __builtin_amdgcn_mfma_f32_32x32x16_bf16(kb, qf[sp], s0, 0, 0, 0);
                else          s1 = __builtin_amdgcn_mfma_f32_32x32x16_bf16(kb, qf[sp], s1, 0, 0, 0);
            }
        }
        __builtin_amdgcn_s_setprio(0);

        float vmax = -INFINITY;
        #pragma unroll
        for (int j = 0; j < 16; ++j) vmax = fmaxf(vmax, s0[j]);
        #pragma unroll
        for (int j = 0; j < 16; ++j) vmax = fmaxf(vmax, s1[j]);
        vmax = fmaxf(vmax, __shfl_xor(vmax, 32));

        if (!__all(vmax - m_run <= THR)) {
            const float mnew = fmaxf(m_run, vmax);
            const float alpha = __builtin_amdgcn_exp2f(m_run - mnew);
            m_run = mnew;
            l_run *= alpha;
            #pragma unroll
            for (int r = 0; r < 16; ++r) {
                const int ql = (r & 3) + 8 * (r >> 2) + 4 * hi;
                const float ar = __shfl(alpha, ql + (hi << 5));
                acc0[r] *= ar;
                acc1[r] *= ar;
            }
        }

        float rs = 0.f;
        #pragma unroll
        for (int j = 0; j < 16; ++j) { const float p = __builtin_amdgcn_exp2f(s0[j] - m_run); s0[j] = p; rs += p; }
        #pragma unroll
        for (int j = 0; j < 16; ++j) { const float p = __builtin_amdgcn_exp2f(s1[j] - m_run); s1[j] = p; rs += p; }
        rs += __shfl_xor(rs, 32);
        l_run += rs;

        frag_cast pa[4];
        #pragma unroll
        for (int b2 = 0; b2 < 2; ++b2) {
            #pragma unroll
            for (int st = 0; st < 2; ++st) {
                uint32_t wa, wb, wc, wd;
                if (b2 == 0) {
                    wa = cvt_pk_bf16(s0[8 * st + 0], s0[8 * st + 1]);
                    wb = cvt_pk_bf16(s0[8 * st + 2], s0[8 * st + 3]);
                    wc = cvt_pk_bf16(s0[8 * st + 4], s0[8 * st + 5]);
                    wd = cvt_pk_bf16(s0[8 * st + 6], s0[8 * st + 7]);
                } else {
                    wa = cvt_pk_bf16(s1[8 * st + 0], s1[8 * st + 1]);
                    wb = cvt_pk_bf16(s1[8 * st + 2], s1[8 * st + 3]);
                    wc = cvt_pk_bf16(s1[8 * st + 4], s1[8 * st + 5]);
                    wd = cvt_pk_bf16(s1[8 * st + 6], s1[8 * st + 7]);
                }
                perm32swap(wa, wc);
                perm32swap(wb, wd);
                pa[2 * b2 + st].u = (u32x4){wa, wb, wc, wd};
            }
        }

        __builtin_amdgcn_s_setprio(1);
        #pragma unroll
        for (int ks = 0; ks < 4; ++ks) {
            #pragma unroll
            for (int dt = 0; dt < 2; ++dt) {
                const int d = dt * 32 + l31;
                const int eo = d * 64 + ((16 * ks + 8 * hi) ^ ((d & 7) << 3));
                bf16x8 vb = *(const bf16x8*)(&Vt[cur][eo]);
                if (dt == 0) acc0 = __builtin_amdgcn_mfma_f32_32x32x16_bf16(pa[ks].h, vb, acc0, 0, 0, 0);
                else         acc1 = __builtin_amdgcn_mfma_f32_32x32x16_bf16(pa[ks].h, vb, acc1, 0, 0, 0);
            }
        }
        __builtin_amdgcn_s_setprio(0);

        if (t + 1 < NT) writeTile(cur ^ 1);
        __syncthreads();
        cur ^= 1;
    }

    float* op = Og + base;
    #pragma unroll
    for (int r = 0; r < 16; ++r) {
        const int ql = (r & 3) + 8 * (r >> 2) + 4 * hi;
        const float lr = __shfl(l_run, ql + (hi << 5));
        const float invl = 1.0f / lr;
        const size_t row = (size_t)(q0g + ql) * DK;
        op[row + l31]      = acc0[r] * invl;
        op[row + 32 + l31] = acc1[r] * invl;
    }
}

extern "C" void kernel_launch(void* const* d_in, const int* in_sizes, int n_in,
                              void* d_out, int out_size, void* d_ws, size_t ws_size,
                              hipStream_t stream) {
    const float* q = (const float*)d_in[0];
    const float* k = (const float*)d_in[1];
    const float* v = (const float*)d_in[2];
    float* o = (float*)d_out;
    const int bh = in_sizes[0] / (S_LEN * DK);   // = 32 for B=2,H=16

    const size_t img_bytes = (size_t)bh * NT * 4096 * sizeof(__bf16); // 8 MB
    if (ws_size >= 2 * img_bytes) {
        __bf16* Kimg = (__bf16*)d_ws;
        __bf16* Vimg = (__bf16*)((char*)d_ws + img_bytes);
        prep_pack<<<dim3(NT, bh), dim3(256), 0, stream>>>(k, v, Kimg, Vimg);
        attn_fwd_lds<<<dim3(S_LEN / QBLK, bh), dim3(256), 0, stream>>>(q, Kimg, Vimg, o);
    } else {
        attn_fwd_fb<<<dim3(S_LEN / QBLK, bh), dim3(256), 0, stream>>>(q, k, v, o);
    }
}